// Round 1
// baseline (3623.009 us; speedup 1.0000x reference)
//
#include <hip/hip_runtime.h>
#include <cmath>
#include <cstdint>
#include <cstddef>

#define BB 256      // batch
#define MM 8192     // checks
#define NN 16384    // variables
#define DEG 10
#define MAX_ITER 30

// ---------------- prologue kernels ----------------

__global__ void k_init(int* colcnt, int* colfill, int* mm, int* niter, int* conv) {
    int t = blockIdx.x * blockDim.x + threadIdx.x;
    if (t < NN) { colcnt[t] = 0; colfill[t] = 0; }
    if (t < BB) { mm[t] = 0; niter[t] = -1; conv[t] = 0; }
}

// transpose f32: in (R,C) row-major -> out (C,R); optional duplicate out2
__global__ void k_transpose_f32(const float* __restrict__ in, float* __restrict__ out,
                                float* __restrict__ out2, int R, int C) {
    __shared__ float tile[64][65];
    int c0 = blockIdx.x * 64;
    int r0 = blockIdx.y * 64;
    #pragma unroll
    for (int k = 0; k < 16; k++) {
        int idx = k * 256 + threadIdx.x;
        int i = idx >> 6, j = idx & 63;
        tile[i][j] = in[(size_t)(r0 + i) * C + (c0 + j)];
    }
    __syncthreads();
    #pragma unroll
    for (int k = 0; k < 16; k++) {
        int idx = k * 256 + threadIdx.x;
        int i = idx >> 6, j = idx & 63;
        float v = tile[j][i];
        size_t o = (size_t)(c0 + i) * R + (r0 + j);
        out[o] = v;
        if (out2) out2[o] = v;
    }
}

// synd (B,M) f32 -> syndb (M,B) byte
__global__ void k_synd_t(const float* __restrict__ synd, unsigned char* __restrict__ syndb) {
    __shared__ float tile[64][65];
    int c0 = blockIdx.x * 64;   // m
    int r0 = blockIdx.y * 64;   // b
    #pragma unroll
    for (int k = 0; k < 16; k++) {
        int idx = k * 256 + threadIdx.x;
        int i = idx >> 6, j = idx & 63;
        tile[i][j] = synd[(size_t)(r0 + i) * MM + (c0 + j)];
    }
    __syncthreads();
    #pragma unroll
    for (int k = 0; k < 16; k++) {
        int idx = k * 256 + threadIdx.x;
        int i = idx >> 6, j = idx & 63;
        syndb[(size_t)(c0 + i) * BB + (r0 + j)] = (tile[j][i] != 0.0f) ? 1 : 0;
    }
}

__global__ void k_hist(const int* __restrict__ vc, int* colcnt) {
    int e = blockIdx.x * 256 + threadIdx.x;
    if (e >= MM * DEG) return;
    int c = vc[e];
    if (c < NN) atomicAdd(&colcnt[c], 1);
}

__global__ void k_scan(const int* __restrict__ colcnt, int* __restrict__ colptr) {
    __shared__ int part[256];
    __shared__ int base[257];
    int t = threadIdx.x;
    int s = 0;
    for (int i = 0; i < 64; i++) s += colcnt[t * 64 + i];
    part[t] = s;
    __syncthreads();
    if (t == 0) {
        int acc = 0;
        for (int i = 0; i < 256; i++) { base[i] = acc; acc += part[i]; }
        base[256] = acc;
    }
    __syncthreads();
    int acc = base[t];
    for (int i = 0; i < 64; i++) { int c = t * 64 + i; colptr[c] = acc; acc += colcnt[c]; }
    if (t == 255) colptr[NN] = base[256];
}

__global__ void k_fill(const int* __restrict__ vc, const int* __restrict__ colptr,
                       int* colfill, int* coledges) {
    int e = blockIdx.x * 256 + threadIdx.x;
    if (e >= MM * DEG) return;
    int c = vc[e];
    if (c < NN) {
        int p = colptr[c] + atomicAdd(&colfill[c], 1);
        coledges[p] = e;
    }
}

// deterministic: sort each column's edge list ascending (order-independent result)
__global__ void k_sort(const int* __restrict__ colptr, int* coledges) {
    int n = blockIdx.x * 256 + threadIdx.x;
    if (n >= NN) return;
    int p0 = colptr[n], p1 = colptr[n + 1];
    for (int i = p0 + 1; i < p1; i++) {
        int v = coledges[i];
        int j = i - 1;
        while (j >= p0 && coledges[j] > v) { coledges[j + 1] = coledges[j]; j--; }
        coledges[j + 1] = v;
    }
}

// ---------------- iteration kernels ----------------

// check-node update: block = m, thread = b
__global__ void k_check(const int* __restrict__ vc, const float* __restrict__ lv,
                        float* __restrict__ msg, const unsigned char* __restrict__ syndb,
                        const int* __restrict__ niter, float beta, int first) {
    __shared__ int cs[DEG];
    int m = blockIdx.x, b = threadIdx.x;
    if (threadIdx.x < DEG) cs[threadIdx.x] = vc[m * DEG + threadIdx.x];
    __syncthreads();
    if (niter[b] != -1) return;

    float ab[DEG];
    float m0 = INFINITY, m1 = INFINITY;
    unsigned neg = 0;
    #pragma unroll
    for (int d = 0; d < DEG; d++) {
        int c = cs[d];
        float a;
        if (c >= NN) {
            a = INFINITY;
        } else {
            float g = lv[(size_t)c * BB + b];
            if (first) a = g;
            else       a = g - msg[(size_t)(m * DEG + d) * BB + b];
        }
        if (!(a > 0.0f)) neg |= 1u << d;   // sign(a<=0) = -1 (matches sign(0)->-1)
        float x = fabsf(a);
        ab[d] = x;
        if (x < m0) { m1 = m0; m0 = x; }
        else if (x < m1) { m1 = x; }
    }
    unsigned q = (__popc(neg) & 1u) ^ (syndb[(size_t)m * BB + b] ? 1u : 0u);
    #pragma unroll
    for (int d = 0; d < DEG; d++) {
        int c = cs[d];
        if (c >= NN) continue;            // dummy: b masked to 0, never read
        float mr = (ab[d] == m0) ? m1 : m0;   // value-equality: exact tie semantics
        float t = beta * mr;                  // single rounding, sign applied exactly
        unsigned s = q ^ ((neg >> d) & 1u);
        msg[(size_t)(m * DEG + d) * BB + b] = s ? -t : t;
    }
}

// variable-node update: block = n, thread = b; deterministic ascending-edge sum
__global__ void k_var(const float* __restrict__ llr0t, const float* __restrict__ msg,
                      const int* __restrict__ colptr, const int* __restrict__ coledges,
                      float* __restrict__ lv, unsigned char* __restrict__ ev,
                      const int* __restrict__ niter) {
    int n = blockIdx.x, b = threadIdx.x;
    if (niter[b] != -1) return;           // frozen batches keep their converged lv/ev
    float s = llr0t[(size_t)n * BB + b];
    int p0 = colptr[n], p1 = colptr[n + 1];
    for (int p = p0; p < p1; p++) {
        int e = coledges[p];
        s += msg[(size_t)e * BB + b];
    }
    lv[(size_t)n * BB + b] = s;
    ev[(size_t)n * BB + b] = (s <= 0.0f) ? 1 : 0;
}

// parity check: block = m, thread = b
__global__ void k_parity(const int* __restrict__ vc, const unsigned char* __restrict__ ev,
                         const unsigned char* __restrict__ syndb, const int* __restrict__ niter,
                         int* __restrict__ mm) {
    int m = blockIdx.x, b = threadIdx.x;
    if (niter[b] != -1) return;
    if (mm[b]) return;                    // cheap early-out (stale read OK)
    unsigned par = 0;
    #pragma unroll
    for (int d = 0; d < DEG; d++) {
        int c = vc[m * DEG + d];
        if (c < NN) par ^= ev[(size_t)c * BB + b];
    }
    if ((par & 1u) != (unsigned)syndb[(size_t)m * BB + b]) atomicOr(&mm[b], 1);
}

__global__ void k_conv(int* niter, int* conv, int* mm, int it) {
    int b = threadIdx.x;
    if (niter[b] == -1 && mm[b] == 0) { niter[b] = it; conv[b] = 1; }
    mm[b] = 0;                            // reset for next iteration
}

// ---------------- epilogue ----------------

__global__ void k_out_e(const unsigned char* __restrict__ ev, float* __restrict__ out) {
    __shared__ float tile[64][65];
    int c0 = blockIdx.x * 64;   // b
    int r0 = blockIdx.y * 64;   // n
    #pragma unroll
    for (int k = 0; k < 16; k++) {
        int idx = k * 256 + threadIdx.x;
        int i = idx >> 6, j = idx & 63;
        tile[i][j] = (float)ev[(size_t)(r0 + i) * BB + (c0 + j)];
    }
    __syncthreads();
    #pragma unroll
    for (int k = 0; k < 16; k++) {
        int idx = k * 256 + threadIdx.x;
        int i = idx >> 6, j = idx & 63;
        out[(size_t)(c0 + i) * NN + (r0 + j)] = tile[j][i];
    }
}

__global__ void k_out_scalars(const int* __restrict__ niter, const int* __restrict__ conv,
                              float* __restrict__ out_ni, float* __restrict__ out_conv) {
    int b = threadIdx.x;
    int ni = niter[b];
    out_ni[b] = (float)(ni == -1 ? MAX_ITER : ni);
    out_conv[b] = (float)conv[b];
}

// ---------------- launch ----------------

extern "C" void kernel_launch(void* const* d_in, const int* in_sizes, int n_in,
                              void* d_out, int out_size, void* d_ws, size_t ws_size,
                              hipStream_t stream) {
    const float* synd = (const float*)d_in[0];   // (B, M)
    const float* llr0 = (const float*)d_in[1];   // (B, N)
    const int* vcol   = (const int*)d_in[3];     // (M, DEG)
    float* out = (float*)d_out;

    char* ws = (char*)d_ws;
    size_t off = 0;
    auto alloc = [&](size_t bytes) {
        off = (off + 255) & ~(size_t)255;
        size_t o = off; off += bytes; return o;
    };
    float* llr0t   = (float*)(ws + alloc((size_t)NN * BB * 4));
    float* lv      = (float*)(ws + alloc((size_t)NN * BB * 4));
    float* msg     = (float*)(ws + alloc((size_t)MM * DEG * BB * 4));
    unsigned char* ev    = (unsigned char*)(ws + alloc((size_t)NN * BB));
    unsigned char* syndb = (unsigned char*)(ws + alloc((size_t)MM * BB));
    int* coledges = (int*)(ws + alloc((size_t)MM * DEG * 4));
    int* colptr   = (int*)(ws + alloc((size_t)(NN + 1) * 4));
    int* colcnt   = (int*)(ws + alloc((size_t)NN * 4));
    int* colfill  = (int*)(ws + alloc((size_t)NN * 4));
    int* mm       = (int*)(ws + alloc((size_t)BB * 4));
    int* niter    = (int*)(ws + alloc((size_t)BB * 4));
    int* conv     = (int*)(ws + alloc((size_t)BB * 4));
    (void)ws_size; (void)in_sizes; (void)n_in; (void)out_size;

    // prologue
    k_init<<<NN / 256, 256, 0, stream>>>(colcnt, colfill, mm, niter, conv);
    k_transpose_f32<<<dim3(NN / 64, BB / 64), 256, 0, stream>>>(llr0, llr0t, lv, BB, NN);
    k_synd_t<<<dim3(MM / 64, BB / 64), 256, 0, stream>>>(synd, syndb);
    k_hist<<<(MM * DEG + 255) / 256, 256, 0, stream>>>(vcol, colcnt);
    k_scan<<<1, 256, 0, stream>>>(colcnt, colptr);
    k_fill<<<(MM * DEG + 255) / 256, 256, 0, stream>>>(vcol, colptr, colfill, coledges);
    k_sort<<<NN / 256, 256, 0, stream>>>(colptr, coledges);

    // main loop
    for (int i = 1; i <= MAX_ITER; i++) {
        float beta = 1.0f - ldexpf(1.0f, -i);
        k_check<<<MM, 256, 0, stream>>>(vcol, lv, msg, syndb, niter, beta, (i == 1) ? 1 : 0);
        k_var<<<NN, 256, 0, stream>>>(llr0t, msg, colptr, coledges, lv, ev, niter);
        k_parity<<<MM, 256, 0, stream>>>(vcol, ev, syndb, niter, mm);
        k_conv<<<1, 256, 0, stream>>>(niter, conv, mm, i);
    }

    // epilogue: e_out | num_iters | l_out | conv
    size_t off_e = 0;
    size_t off_ni = (size_t)BB * NN;
    size_t off_l = off_ni + BB;
    size_t off_c = off_l + (size_t)BB * NN;
    k_out_e<<<dim3(BB / 64, NN / 64), 256, 0, stream>>>(ev, out + off_e);
    k_transpose_f32<<<dim3(BB / 64, NN / 64), 256, 0, stream>>>(lv, out + off_l, nullptr, NN, BB);
    k_out_scalars<<<1, 256, 0, stream>>>(niter, conv, out + off_ni, out + off_c);
}